// Round 8
// baseline (519.037 us; speedup 1.0000x reference)
//
#include <hip/hip_runtime.h>
#include <hip/hip_bf16.h>
#include <math.h>

// ---------------------------------------------------------------------------
// GCN predictor: 2x GCNConv(relu) -> mean pool + global feats -> MLP head
// N=100K nodes, E=3.2M directed edges, H=64.
// R8: split k_l2fuse into pure-gather (8-way interleaved, max MLP) +
// dense shfl-matmul kernel (W2 in VGPRs). gf fused into k_csr; red memset
// fused into k_scanA. agg2 aliases the dead records buffer.
// ---------------------------------------------------------------------------

#define BUCKET 256
#define MAXB   512   // max buckets / max chunks (needs n <= 131072)

// per-chunk bucket histogram: gcounts[chunk*NBK + bucket]
__global__ void k_hist(const int* __restrict__ dst, int E, int chunk,
                       int* __restrict__ gcounts, int NBK) {
    __shared__ int lcnt[MAXB];
    for (int i = threadIdx.x; i < NBK; i += blockDim.x) lcnt[i] = 0;
    __syncthreads();
    int e0 = blockIdx.x * chunk;
    int e1 = min(e0 + chunk, E);
    for (int e = e0 + threadIdx.x; e < e1; e += blockDim.x)
        atomicAdd(&lcnt[dst[e] >> 8], 1);
    __syncthreads();
    for (int b = threadIdx.x; b < NBK; b += blockDim.x)
        gcounts[blockIdx.x * NBK + b] = lcnt[b];
}

// single block: bucket_base[b] = exclusive scan of per-bucket totals
// also zero-inits the red[] accumulator (saves a memset dispatch)
__global__ void k_scanA(const int* __restrict__ gcounts, int* __restrict__ bucket_base,
                        float* __restrict__ red, int NBK, int NCH) {
    __shared__ int lds[MAXB];
    int t = threadIdx.x;
    if (t < 96) red[t] = 0.f;
    int tot = 0;
    if (t < NBK)
        for (int c = 0; c < NCH; ++c) tot += gcounts[c * NBK + t];
    lds[t] = tot;
    __syncthreads();
    for (int off = 1; off < MAXB; off <<= 1) {
        int add = (t >= off) ? lds[t - off] : 0;
        __syncthreads();
        lds[t] += add;
        __syncthreads();
    }
    if (t < NBK) bucket_base[t] = lds[t] - tot;
    if (t == NBK - 1) bucket_base[NBK] = lds[t];
}

// per bucket: scan counts across chunks, in place:
// gcounts[c*NBK+b] becomes the global slot base for (chunk c, bucket b)
__global__ void k_scanB(int* __restrict__ gcounts, const int* __restrict__ bucket_base,
                        int NBK, int NCH) {
    __shared__ int lds[MAXB];
    int b = blockIdx.x;
    int t = threadIdx.x;
    int v = (t < NCH) ? gcounts[t * NBK + b] : 0;
    lds[t] = v;
    __syncthreads();
    for (int off = 1; off < MAXB; off <<= 1) {
        int add = (t >= off) ? lds[t - off] : 0;
        __syncthreads();
        lds[t] += add;
        __syncthreads();
    }
    if (t < NCH) gcounts[t * NBK + b] = bucket_base[b] + lds[t] - v;
}

// scatter packed records (local_d<<17 | src) into bucket-grouped order
__global__ void k_bucketize(const int* __restrict__ src, const int* __restrict__ dst,
                            int E, int chunk, const int* __restrict__ gcounts,
                            int* __restrict__ records, int NBK) {
    __shared__ int lcur[MAXB];
    for (int b = threadIdx.x; b < NBK; b += blockDim.x)
        lcur[b] = gcounts[blockIdx.x * NBK + b];
    __syncthreads();
    int e0 = blockIdx.x * chunk;
    int e1 = min(e0 + chunk, E);
    for (int e = e0 + threadIdx.x; e < e1; e += blockDim.x) {
        int d = dst[e];
        int b = d >> 8;
        int rec = ((d & 255) << 17) | src[e];
        int slot = atomicAdd(&lcur[b], 1);
        records[slot] = rec;
    }
}

// per-bucket CSR finalize + xs prescale + global-feature reduction:
// histogram local nodes, LDS scan -> pos/rowend/dinv, scatter src into
// per-node-contiguous ssrc; epilogue writes xs[i]=dinv[i]*x[i] and
// accumulates gf partial sums (n_comp/n_and/n_or/avg terms) into red[64..69].
__global__ void k_csr(const int* __restrict__ records, const int* __restrict__ bucket_base,
                      const float* __restrict__ x,
                      int* __restrict__ ssrc, int* __restrict__ pos, int* __restrict__ rowend,
                      float* __restrict__ dinv, float* __restrict__ xs,
                      float* __restrict__ red, int n) {
    __shared__ int cnt[BUCKET];
    __shared__ int lds[BUCKET];
    __shared__ int cursor[BUCKET];
    int t = threadIdx.x;
    int b = blockIdx.x;
    cnt[t] = 0;
    __syncthreads();
    int j0 = bucket_base[b], j1 = bucket_base[b + 1];
    for (int j = j0 + t; j < j1; j += BUCKET)
        atomicAdd(&cnt[records[j] >> 17], 1);
    __syncthreads();
    int c = cnt[t];
    lds[t] = c;
    __syncthreads();
    for (int off = 1; off < BUCKET; off <<= 1) {
        int add = (t >= off) ? lds[t - off] : 0;
        __syncthreads();
        lds[t] += add;
        __syncthreads();
    }
    int p = j0 + lds[t] - c;   // exclusive
    cursor[t] = p;
    int node = b * BUCKET + t;
    float s2 = 0.f, s3 = 0.f, s4 = 0.f, sm0 = 0.f, sm1 = 0.f, sc = 0.f;
    if (node < n) {
        pos[node] = p;
        rowend[node] = p + c;
        float d = rsqrtf((float)(c + 1));
        dinv[node] = d;
        float x0 = x[node * 5 + 0], x1 = x[node * 5 + 1], x2 = x[node * 5 + 2];
        float x3 = x[node * 5 + 3], x4 = x[node * 5 + 4];
        float4 o;
        o.x = x0 * d; o.y = x1 * d; o.z = x2 * d; o.w = x3 * d;
        ((float4*)xs)[node * 2] = o;
        xs[node * 8 + 4] = x4 * d;
        s2 = x2; s3 = x3; s4 = x4;
        if (x2 == 1.0f) { sm0 = x0; sm1 = x1; sc = 1.f; }
    }
#pragma unroll
    for (int off = 32; off; off >>= 1) {
        s2 += __shfl_down(s2, off);
        s3 += __shfl_down(s3, off);
        s4 += __shfl_down(s4, off);
        sm0 += __shfl_down(sm0, off);
        sm1 += __shfl_down(sm1, off);
        sc += __shfl_down(sc, off);
    }
    if ((t & 63) == 0) {
        atomicAdd(&red[64], s2);
        atomicAdd(&red[65], s3);
        atomicAdd(&red[66], s4);
        atomicAdd(&red[67], sm0);
        atomicAdd(&red[68], sm1);
        atomicAdd(&red[69], sc);
    }
    __syncthreads();
    for (int j = j0 + t; j < j1; j += BUCKET) {
        int rec = records[j];
        int slot = atomicAdd(&cursor[rec >> 17], 1);
        ssrc[slot] = rec & 131071;
    }
}

// 5-dim aggregation: agg5[i,:] = dinv[i] * ( sum_{s in N(i)} xs[s,:] + xs[i,:] )
// thread per node; xs is ~3MB -> L2-resident gathers
__global__ void k_agg5(const int* __restrict__ pos, const int* __restrict__ rowend,
                       const int* __restrict__ ssrc, const float* __restrict__ dinv,
                       const float* __restrict__ xs, float* __restrict__ agg5, int n) {
    int i = blockIdx.x * blockDim.x + threadIdx.x;
    if (i >= n) return;
    const float4* xs4 = (const float4*)xs;
    float4 a = xs4[i * 2];            // self term
    float a4 = xs[i * 8 + 4];
    int beg = pos[i], end = rowend[i];
    int j = beg;
    for (; j + 1 < end; j += 2) {
        int s0 = ssrc[j], s1 = ssrc[j + 1];
        float4 v0 = xs4[s0 * 2]; float w0 = xs[s0 * 8 + 4];
        float4 v1 = xs4[s1 * 2]; float w1 = xs[s1 * 8 + 4];
        a.x += v0.x + v1.x; a.y += v0.y + v1.y;
        a.z += v0.z + v1.z; a.w += v0.w + v1.w;
        a4 += w0 + w1;
    }
    for (; j < end; ++j) {
        int s = ssrc[j];
        float4 v = xs4[s * 2];
        a.x += v.x; a.y += v.y; a.z += v.z; a.w += v.w;
        a4 += xs[s * 8 + 4];
    }
    float dd = dinv[i];
    float4 o; o.x = a.x * dd; o.y = a.y * dd; o.z = a.z * dd; o.w = a.w * dd;
    ((float4*)agg5)[i * 2] = o;
    agg5[i * 8 + 4] = a4 * dd;
}

// h1s[i,f] = bf16( dinv[i] * relu( agg5[i,:] @ W1[:,f] + b1[f] ) )  (wave/node)
__global__ void k_h1(const float* __restrict__ agg5, const float* __restrict__ W1,
                     const float* __restrict__ b1, const float* __restrict__ dinv,
                     __hip_bfloat16* __restrict__ h1s, int n) {
    int t = blockIdx.x * blockDim.x + threadIdx.x;
    int i = t >> 6, f = t & 63;
    if (i >= n) return;
    float a0 = agg5[i * 8 + 0], a1 = agg5[i * 8 + 1], a2 = agg5[i * 8 + 2];
    float a3 = agg5[i * 8 + 3], a4 = agg5[i * 8 + 4];
    float v = a0 * W1[f] + a1 * W1[64 + f] + a2 * W1[128 + f]
            + a3 * W1[192 + f] + a4 * W1[256 + f] + b1[f];
    h1s[(size_t)i * 64 + f] = __float2bfloat16(dinv[i] * fmaxf(v, 0.f));
}

// Layer-2 pure gather, 8 nodes per wave lockstep (clamped predicated streams).
// agg2[i,f] = h1s[i,f] + sum_{s in N(i)} h1s[s,f]   (stored bf16)
__global__ __launch_bounds__(256)
void k_l2gather(const int* __restrict__ pos, const int* __restrict__ rowend,
                const int* __restrict__ ssrc, const __hip_bfloat16* __restrict__ h1s,
                __hip_bfloat16* __restrict__ agg2, int n) {
    int t = threadIdx.x, f = t & 63;
    int w = blockIdx.x * (blockDim.x >> 6) + (t >> 6);
    int nw = gridDim.x * (blockDim.x >> 6);
    int nt = (n + 7) >> 3;
    for (int task = w; task < nt; task += nw) {
        int base = task * 8;
#define STRM_INIT(q) \
        int i##q = base + q; bool v##q = i##q < n; \
        int p##q = v##q ? pos[i##q] : 0; \
        int e##q = v##q ? rowend[i##q] : 0; \
        float a##q = v##q ? __bfloat162float(h1s[(size_t)i##q * 64 + f]) : 0.f;
        STRM_INIT(0) STRM_INIT(1) STRM_INIT(2) STRM_INIT(3)
        STRM_INIT(4) STRM_INIT(5) STRM_INIT(6) STRM_INIT(7)
#undef STRM_INIT
        int len = max(max(max(e0 - p0, e1 - p1), max(e2 - p2, e3 - p3)),
                      max(max(e4 - p4, e5 - p5), max(e6 - p6, e7 - p7)));
#pragma unroll 2
        for (int m = 0; m < len; ++m) {
#define STRM_STEP(q) \
            { int j = p##q + m; \
              int s = ssrc[j < e##q ? j : 0]; \
              float g = __bfloat162float(h1s[(size_t)s * 64 + f]); \
              if (j < e##q) a##q += g; }
            STRM_STEP(0) STRM_STEP(1) STRM_STEP(2) STRM_STEP(3)
            STRM_STEP(4) STRM_STEP(5) STRM_STEP(6) STRM_STEP(7)
#undef STRM_STEP
        }
#define STRM_OUT(q) \
        if (v##q) agg2[(size_t)i##q * 64 + f] = __float2bfloat16(a##q);
        STRM_OUT(0) STRM_OUT(1) STRM_OUT(2) STRM_OUT(3)
        STRM_OUT(4) STRM_OUT(5) STRM_OUT(6) STRM_OUT(7)
#undef STRM_OUT
    }
}

// Dense epilogue: out[i,f] = relu( dinv[i]*(agg2[i,:]@W2[:,f]) + b2[f] ),
// mean-pool partial sums into red[0..63]. W2 column f cached in 64 VGPRs.
__global__ __launch_bounds__(256)
void k_l2mm(const __hip_bfloat16* __restrict__ agg2, const float* __restrict__ dinv,
            const float* __restrict__ W2, const float* __restrict__ b2,
            float* __restrict__ red, int n) {
    __shared__ float red64[64];
    int t = threadIdx.x, f = t & 63;
    if (t < 64) red64[t] = 0.f;
    __syncthreads();
    float w2r[64];
#pragma unroll
    for (int k = 0; k < 64; ++k) w2r[k] = W2[k * 64 + f];
    float bf = b2[f];
    int w = blockIdx.x * (blockDim.x >> 6) + (t >> 6);
    int nw = gridDim.x * (blockDim.x >> 6);
    float psum = 0.f;
    for (int i = w; i < n; i += nw) {
        float a = __bfloat162float(agg2[(size_t)i * 64 + f]);
        float q0 = 0.f, q1 = 0.f;
#pragma unroll
        for (int k = 0; k < 64; k += 2) {
            q0 += __shfl(a, k) * w2r[k];
            q1 += __shfl(a, k + 1) * w2r[k + 1];
        }
        psum += fmaxf((q0 + q1) * dinv[i] + bf, 0.f);
    }
    atomicAdd(&red64[f], psum);
    __syncthreads();
    if (t < 64) atomicAdd(&red[t], red64[t]);
}

// Final head: emb = [mean(h2), gf(6)] (70), MLP 70->32->2, 2+3*sigmoid
__global__ void k_head(const float* __restrict__ red,
                       const float* __restrict__ l1w, const float* __restrict__ l1b,
                       const float* __restrict__ l2w, const float* __restrict__ l2b,
                       float* __restrict__ out, int n) {
    __shared__ float emb[70];
    __shared__ float hid[32];
    int t = threadIdx.x;
    if (t < 64) emb[t] = red[t] / (float)n;
    if (t == 0) {
        float n_comp = red[64], n_and = red[65], n_or = red[66];
        float cnt = red[69];
        float safe = fmaxf(cnt, 1.f);
        emb[64] = n_comp;
        emb[65] = n_and;
        emb[66] = n_or;
        emb[67] = n_and + n_or;
        emb[68] = cnt > 0.f ? red[67] / safe : 0.f;
        emb[69] = cnt > 0.f ? red[68] / safe : 0.f;
    }
    __syncthreads();
    if (t < 32) {
        float acc = l1b[t];
#pragma unroll
        for (int k = 0; k < 70; ++k) acc += emb[k] * l1w[k * 32 + t];
        hid[t] = fmaxf(acc, 0.f);
    }
    __syncthreads();
    if (t < 2) {
        float acc = l2b[t];
#pragma unroll
        for (int j = 0; j < 32; ++j) acc += hid[j] * l2w[j * 2 + t];
        out[t] = 2.0f + 3.0f / (1.0f + expf(-acc));
    }
}

extern "C" void kernel_launch(void* const* d_in, const int* in_sizes, int n_in,
                              void* d_out, int out_size, void* d_ws, size_t ws_size,
                              hipStream_t stream) {
    const float* x   = (const float*)d_in[0];
    const int*   ei  = (const int*)d_in[1];
    const float* w1  = (const float*)d_in[2];
    const float* b1  = (const float*)d_in[3];
    const float* w2  = (const float*)d_in[4];
    const float* b2  = (const float*)d_in[5];
    const float* l1w = (const float*)d_in[6];
    const float* l1b = (const float*)d_in[7];
    const float* l2w = (const float*)d_in[8];
    const float* l2b = (const float*)d_in[9];

    const int n = in_sizes[0] / 5;
    const int E = in_sizes[1] / 2;
    const int* src = ei;
    const int* dst = ei + E;

    const int NBK = (n + BUCKET - 1) / BUCKET;   // 391 buckets
    const int NCH = NBK;                          // edge chunks
    const int chunk = (E + NCH - 1) / NCH;

    size_t nf = (size_t)n * 64;
    __hip_bfloat16* h1s = (__hip_bfloat16*)d_ws;      // N x 64 bf16 prescaled
    float* xs          = (float*)(h1s + nf);          // N x 8 (padded)
    float* agg5        = xs + (size_t)n * 8;          // N x 8 (padded)
    float* dinv        = agg5 + (size_t)n * 8;
    float* red         = dinv + n;                    // 96 floats
    int*   pos         = (int*)(red + 96);
    int*   rowend      = pos + n;
    int*   bucket_base = rowend + n;                  // NBK+1
    int*   gcounts     = bucket_base + (MAXB + 8);    // NCH*NBK
    int*   records     = gcounts + NCH * NBK;         // E ints (dead after k_csr)
    int*   ssrc        = records + E;                 // E ints, per-node CSR
    __hip_bfloat16* agg2 = (__hip_bfloat16*)records;  // N x 64 bf16, aliases records

    k_hist<<<NCH, 512, 0, stream>>>(dst, E, chunk, gcounts, NBK);
    k_scanA<<<1, MAXB, 0, stream>>>(gcounts, bucket_base, red, NBK, NCH);
    k_scanB<<<NBK, MAXB, 0, stream>>>(gcounts, bucket_base, NBK, NCH);
    k_bucketize<<<NCH, 512, 0, stream>>>(src, dst, E, chunk, gcounts, records, NBK);
    k_csr<<<NBK, BUCKET, 0, stream>>>(records, bucket_base, x, ssrc, pos, rowend,
                                      dinv, xs, red, n);

    k_agg5<<<(n + 255) / 256, 256, 0, stream>>>(pos, rowend, ssrc, dinv, xs, agg5, n);
    k_h1<<<(int)((nf + 255) / 256), 256, 0, stream>>>(agg5, w1, b1, dinv, h1s, n);

    const int nt = (n + 7) >> 3;
    const int gblocks = (nt + 3) / 4;                 // 1 task per wave
    k_l2gather<<<gblocks, 256, 0, stream>>>(pos, rowend, ssrc, h1s, agg2, n);
    k_l2mm<<<2048, 256, 0, stream>>>(agg2, dinv, w2, b2, red, n);

    k_head<<<1, 64, 0, stream>>>(red, l1w, l1b, l2w, l2b, (float*)d_out, n);
}